// Round 2
// baseline (478.046 us; speedup 1.0000x reference)
//
#include <hip/hip_runtime.h>
#include <math.h>

#define NHID 1024
#define NCLS 224
#define NTPC 225
#define BATCH 2048
#define YP 228   // y_lds row pitch (floats)

// ws layout (bytes):
// [0,      8192): tp   float[2048]
// [8192,  16384): cls  int[2048]
// [16384, 24576): pos  int[2048]
// [24576, 32768): list int[2048]
// [32768, 33768): offs int[225]

// ---------------------------------------------------------------------------
// Pass 0: label decode (int32/int64 autodetect), class/pos, group-by-class.
// ---------------------------------------------------------------------------
__global__ __launch_bounds__(256) void group_kernel(const int* __restrict__ labels,
                                                    int* __restrict__ cls,
                                                    int* __restrict__ pos,
                                                    int* __restrict__ list,
                                                    int* __restrict__ offs) {
    __shared__ int cnt[NCLS];
    __shared__ int sc[256];
    __shared__ int bex[NCLS];
    __shared__ int nz;
    const int tid = threadIdx.x;
    if (tid == 0) nz = 0;
    for (int j = tid; j < NCLS; j += 256) cnt[j] = 0;
    __syncthreads();
    // dtype probe: first 2048 words valid for both dtypes; int64<2^31 -> odd words 0
    int loc = 0;
    for (int k = 0; k < 4; ++k) {
        int i = tid + 256 * k;
        if (labels[2 * i + 1] != 0) loc = 1;
    }
    if (loc) atomicOr(&nz, 1);
    __syncthreads();
    const bool is64 = (nz == 0);
    int myc[8], myr[8];
#pragma unroll
    for (int k = 0; k < 8; ++k) {
        int i = tid + 256 * k;
        int l = is64 ? labels[2 * i] : labels[i];
        int c = l / NTPC;
        cls[i] = c;
        pos[i] = l - c * NTPC;
        myc[k] = c;
        myr[k] = atomicAdd(&cnt[c], 1);
    }
    __syncthreads();
    // parallel inclusive scan of cnt over 256 slots
    int v = (tid < NCLS) ? cnt[tid] : 0;
    sc[tid] = v;
    __syncthreads();
    for (int off = 1; off < 256; off <<= 1) {
        int u = (tid >= off) ? sc[tid - off] : 0;
        __syncthreads();
        sc[tid] += u;
        __syncthreads();
    }
    if (tid < NCLS) {
        int ex = sc[tid] - v;      // exclusive
        bex[tid] = ex;
        offs[tid] = ex;
    }
    if (tid == 0) offs[NCLS] = BATCH;
    __syncthreads();
#pragma unroll
    for (int k = 0; k < 8; ++k) {
        int i = tid + 256 * k;
        list[bex[myc[k]] + myr[k]] = i;
    }
}

// ---------------------------------------------------------------------------
// Pass 1: top GEMM + softmax -> tp[b].
// 8-sample tiles x 256 blocks. 16 waves K-split. x transposed+swizzled in LDS,
// read as lane-uniform ds_read_b128.  slot(i,h) = ((i&3)^((h>>2)&3)) + 4*((i>>2)^(h&1))
// ---------------------------------------------------------------------------
__global__ __launch_bounds__(1024) void top_kernel(const float* __restrict__ x,
                                                   const float* __restrict__ Wt,
                                                   const float* __restrict__ bt,
                                                   const int* __restrict__ cls,
                                                   float* __restrict__ tp) {
    __shared__ __align__(16) float xT[1024 * 8];   // 32 KB; overlaid by y[8][YP] later
    float* yl = xT;
    const int tid = threadIdx.x;
    const int w = tid >> 6, l = tid & 63;
    const int sb = blockIdx.x * 8;

    { // stage: wave w -> sample w>>1, half (w&1)
        const int i = w >> 1;
        const float* xr = x + (size_t)(sb + i) * NHID;
        const int hbase = (w & 1) * 512;
#pragma unroll
        for (int j = 0; j < 8; ++j) {
            int h = hbase + l + 64 * j;
            float v = xr[h];
            int slot = ((i & 3) ^ ((h >> 2) & 3)) + 4 * ((i >> 2) ^ (h & 1));
            xT[h * 8 + slot] = v;
        }
    }
    __syncthreads();

    float acc[2][4][4];
#pragma unroll
    for (int q = 0; q < 2; ++q)
#pragma unroll
        for (int m = 0; m < 4; ++m)
#pragma unroll
            for (int g = 0; g < 4; ++g) acc[q][m][g] = 0.f;

    const int qq = w & 1;
    const int qx = (w >> 2) & 3;
    const float* wrow = Wt + (size_t)w * NCLS + l;
#pragma unroll 4
    for (int j = 0; j < 64; ++j) {
        const int h = w + 16 * j;
        float4 xv[2];
#pragma unroll
        for (int qs = 0; qs < 2; ++qs)
            xv[qs] = *(const float4*)&xT[h * 8 + 4 * (qs ^ qq)];
        float wv[4];
        wv[0] = wrow[0]; wv[1] = wrow[64]; wv[2] = wrow[128];
        wv[3] = (l < 32) ? wrow[192] : 0.f;
#pragma unroll
        for (int qs = 0; qs < 2; ++qs) {
            const float xm[4] = {xv[qs].x, xv[qs].y, xv[qs].z, xv[qs].w};
#pragma unroll
            for (int m = 0; m < 4; ++m)
#pragma unroll
                for (int g = 0; g < 4; ++g)
                    acc[qs][m][g] = fmaf(xm[m], wv[g], acc[qs][m][g]);
        }
        wrow += 16 * NCLS;
    }
    __syncthreads();
    for (int k = tid; k < 8 * YP; k += 1024) yl[k] = 0.f;
    __syncthreads();
#pragma unroll
    for (int qs = 0; qs < 2; ++qs)
#pragma unroll
        for (int m = 0; m < 4; ++m) {
            int i = 4 * qs + (m ^ qx);
#pragma unroll
            for (int g = 0; g < 4; ++g) {
                int col = l + 64 * g;
                if (col < NCLS) atomicAdd(&yl[i * YP + col], acc[qs][m][g]);
            }
        }
    __syncthreads();
    if (w < 8) {
        float v[4];
#pragma unroll
        for (int g = 0; g < 4; ++g) {
            int col = l + 64 * g;
            v[g] = (col < NCLS) ? yl[w * YP + col] + bt[col] : -INFINITY;
        }
        float mx = fmaxf(fmaxf(v[0], v[1]), fmaxf(v[2], v[3]));
#pragma unroll
        for (int off = 32; off; off >>= 1) mx = fmaxf(mx, __shfl_xor(mx, off));
        float e[4], sum = 0.f;
#pragma unroll
        for (int g = 0; g < 4; ++g) {
            int col = l + 64 * g;
            e[g] = (col < NCLS) ? __expf(v[g] - mx) : 0.f;
            sum += e[g];
        }
#pragma unroll
        for (int off = 32; off; off >>= 1) sum += __shfl_xor(sum, off);
        int ct = cls[sb + w];
#pragma unroll
        for (int g = 0; g < 4; ++g)
            if (l + 64 * g == ct) tp[sb + w] = e[g] / sum;
    }
}

// ---------------------------------------------------------------------------
// Pass 2: per-class bottom GEMM + softmax + product. One class/block.
// 16-sample tiles, 16-wave K-split, NQ (sample quads) templated.
// slot(i,h) = ((i&3)^((h>>2)&3)) + 4*((i>>2)^(h&3))
// ---------------------------------------------------------------------------
template <int NQ>
__device__ __forceinline__ void bottom_compute(const float* __restrict__ Wc,
                                               const float* __restrict__ xT,
                                               float* __restrict__ yl,
                                               int w, int l, int tid) {
    float acc[NQ][4][4];
#pragma unroll
    for (int q = 0; q < NQ; ++q)
#pragma unroll
        for (int m = 0; m < 4; ++m)
#pragma unroll
            for (int g = 0; g < 4; ++g) acc[q][m][g] = 0.f;
    const int qq = w & 3;
    const int qx = (w >> 2) & 3;
    const float* wrow = Wc + (size_t)w * NTPC + l;
#pragma unroll 2
    for (int j = 0; j < 64; ++j) {
        const int h = w + 16 * j;
        float4 xv[NQ];
#pragma unroll
        for (int qs = 0; qs < NQ; ++qs)
            xv[qs] = *(const float4*)&xT[(h << 4) + 4 * (qs ^ qq)];
        float wv[4];
        wv[0] = wrow[0]; wv[1] = wrow[64]; wv[2] = wrow[128];
        wv[3] = (l < 33) ? wrow[192] : 0.f;
#pragma unroll
        for (int qs = 0; qs < NQ; ++qs) {
            const float xm[4] = {xv[qs].x, xv[qs].y, xv[qs].z, xv[qs].w};
#pragma unroll
            for (int m = 0; m < 4; ++m)
#pragma unroll
                for (int g = 0; g < 4; ++g)
                    acc[qs][m][g] = fmaf(xm[m], wv[g], acc[qs][m][g]);
        }
        wrow += 16 * NTPC;
    }
    __syncthreads();                          // xT reads done
    for (int k = tid; k < 16 * YP; k += 1024) yl[k] = 0.f;
    __syncthreads();
#pragma unroll
    for (int qs = 0; qs < NQ; ++qs)
#pragma unroll
        for (int m = 0; m < 4; ++m) {
            int i = 4 * qs + (m ^ qx);
#pragma unroll
            for (int g = 0; g < 4; ++g) {
                int col = l + 64 * g;
                if (col < NTPC) atomicAdd(&yl[i * YP + col], acc[qs][m][g]);
            }
        }
    __syncthreads();
}

__global__ __launch_bounds__(1024) void bottom_kernel(const float* __restrict__ x,
                                                      const float* __restrict__ Wb,
                                                      const float* __restrict__ bb,
                                                      const int* __restrict__ pos,
                                                      const float* __restrict__ tp,
                                                      const int* __restrict__ list,
                                                      const int* __restrict__ offs,
                                                      float* __restrict__ out) {
    __shared__ __align__(16) float xT[1024 * 16];   // 64 KB; overlaid by y[16][YP]
    float* yl = xT;
    const int tid = threadIdx.x;
    const int w = tid >> 6, l = tid & 63;
    const int c = blockIdx.x;
    const int o = offs[c], n = offs[c + 1] - o;
    const float* Wc = Wb + (size_t)c * (NHID * NTPC);

    for (int tb = 0; tb * 16 < n; ++tb) {
        if (tb) __syncthreads();      // epilogue reads of yl vs restage of xT
        {   // stage: wave w stages tile-sample w
            int idx = tb * 16 + w;
            int s_ = list[o + min(idx, n - 1)];
            const float* xr = x + (size_t)s_ * NHID;
#pragma unroll
            for (int j = 0; j < 16; ++j) {
                int h = l + 64 * j;
                float v = xr[h];
                int slot = ((w & 3) ^ ((h >> 2) & 3)) + 4 * ((w >> 2) ^ (h & 3));
                xT[(h << 4) + slot] = v;
            }
        }
        __syncthreads();
        const int nt = min(n - tb * 16, 16);
        const int nq = (nt + 3) >> 2;
        switch (nq) {
            case 1: bottom_compute<1>(Wc, xT, yl, w, l, tid); break;
            case 2: bottom_compute<2>(Wc, xT, yl, w, l, tid); break;
            case 3: bottom_compute<3>(Wc, xT, yl, w, l, tid); break;
            default: bottom_compute<4>(Wc, xT, yl, w, l, tid); break;
        }
        if (w < nt) {   // wave w: softmax for its sample
            int s_ = list[o + tb * 16 + w];
            float v[4];
#pragma unroll
            for (int g = 0; g < 4; ++g) {
                int col = l + 64 * g;
                v[g] = (col < NTPC) ? yl[w * YP + col] + bb[c * NTPC + col] : -INFINITY;
            }
            float mx = fmaxf(fmaxf(v[0], v[1]), fmaxf(v[2], v[3]));
#pragma unroll
            for (int off = 32; off; off >>= 1) mx = fmaxf(mx, __shfl_xor(mx, off));
            float e[4], sum = 0.f;
#pragma unroll
            for (int g = 0; g < 4; ++g) {
                int col = l + 64 * g;
                e[g] = (col < NTPC) ? __expf(v[g] - mx) : 0.f;
                sum += e[g];
            }
#pragma unroll
            for (int off = 32; off; off >>= 1) sum += __shfl_xor(sum, off);
            int p = pos[s_];
            float tv = tp[s_];
#pragma unroll
            for (int g = 0; g < 4; ++g)
                if (l + 64 * g == p) out[s_] = tv * e[g] / sum;
        }
    }
}

extern "C" void kernel_launch(void* const* d_in, const int* in_sizes, int n_in,
                              void* d_out, int out_size, void* d_ws, size_t ws_size,
                              hipStream_t stream) {
    const float* inputs = (const float*)d_in[0];
    const int*   labels = (const int*)d_in[1];
    const float* topW   = (const float*)d_in[2];
    const float* topB   = (const float*)d_in[3];
    const float* botW   = (const float*)d_in[4];
    const float* botB   = (const float*)d_in[5];
    float* out = (float*)d_out;

    char* ws   = (char*)d_ws;
    float* tp  = (float*)(ws);
    int*   cls = (int*)(ws + 8192);
    int*   pos = (int*)(ws + 16384);
    int*   lst = (int*)(ws + 24576);
    int*   off = (int*)(ws + 32768);

    group_kernel<<<1, 256, 0, stream>>>(labels, cls, pos, lst, off);
    top_kernel<<<256, 1024, 0, stream>>>(inputs, topW, topB, cls, tp);
    bottom_kernel<<<224, 1024, 0, stream>>>(inputs, botW, botB, pos, tp, lst, off, out);
}

// Round 3
// 344.390 us; speedup vs baseline: 1.3881x; 1.3881x over previous
//
#include <hip/hip_runtime.h>
#include <math.h>

#define NHID  1024
#define NCLS  224
#define NTPC  225
#define BATCH 2048
#define XP    18          // xs pitch (floats): 4-way-bank-conflict staging, 8B-aligned reads

#define NBOT_BLOCKS (NCLS * 4)      // 896: class c, chunk k (256 rows each)
#define NTOP_BLOCKS (128 * 4)       // 512: sample-tile st, chunk k

// ws layout (bytes):
// [0,      8192): cls  int[2048]
// [8192,  16384): pos  int[2048]
// [16384, 24576): list int[2048]
// [24576, 25480): offs int[226]
// [32768, 32768+2048*224*4): ytop
// [ytop_end, +2048*225*4):   ybot
#define CLS_OFF  0
#define POS_OFF  8192
#define LIST_OFF 16384
#define OFFS_OFF 24576
#define YTOP_OFF 32768
#define YTOP_BYTES (BATCH * NCLS * 4)
#define YBOT_OFF (YTOP_OFF + YTOP_BYTES)
#define YBOT_BYTES (BATCH * NTPC * 4)

// ---------------------------------------------------------------------------
// Pass 0: label decode (int32/int64 autodetect), class/pos, group-by-class.
// ---------------------------------------------------------------------------
__global__ __launch_bounds__(256) void group_kernel(const int* __restrict__ labels,
                                                    int* __restrict__ cls,
                                                    int* __restrict__ pos,
                                                    int* __restrict__ list,
                                                    int* __restrict__ offs) {
    __shared__ int cnt[NCLS];
    __shared__ int sc[256];
    __shared__ int bex[NCLS];
    __shared__ int nz;
    const int tid = threadIdx.x;
    if (tid == 0) nz = 0;
    for (int j = tid; j < NCLS; j += 256) cnt[j] = 0;
    __syncthreads();
    int loc = 0;
    for (int k = 0; k < 4; ++k) {
        int i = tid + 256 * k;
        if (labels[2 * i + 1] != 0) loc = 1;
    }
    if (loc) atomicOr(&nz, 1);
    __syncthreads();
    const bool is64 = (nz == 0);
    int myc[8], myr[8];
#pragma unroll
    for (int k = 0; k < 8; ++k) {
        int i = tid + 256 * k;
        int l = is64 ? labels[2 * i] : labels[i];
        int c = l / NTPC;
        cls[i] = c;
        pos[i] = l - c * NTPC;
        myc[k] = c;
        myr[k] = atomicAdd(&cnt[c], 1);
    }
    __syncthreads();
    int v = (tid < NCLS) ? cnt[tid] : 0;
    sc[tid] = v;
    __syncthreads();
    for (int off = 1; off < 256; off <<= 1) {
        int u = (tid >= off) ? sc[tid - off] : 0;
        __syncthreads();
        sc[tid] += u;
        __syncthreads();
    }
    if (tid < NCLS) {
        int ex = sc[tid] - v;
        bex[tid] = ex;
        offs[tid] = ex;
    }
    if (tid == 0) offs[NCLS] = BATCH;
    __syncthreads();
#pragma unroll
    for (int k = 0; k < 8; ++k) {
        int i = tid + 256 * k;
        list[bex[myc[k]] + myr[k]] = i;
    }
}

// ---------------------------------------------------------------------------
// Pass 1 (fused): partial GEMMs for top and bottom, K-split into 4 chunks of
// 256 rows. 256 threads = 4 waves; wave w owns samples 4w..4w+3; lane l owns
// cols {l, 64+l, 128+l, 192+l}. acc[4][4] = 16 VGPRs -> no spill.
// x-tile in LDS as xs[h][i] (pitch XP=18): reads are wave-uniform ds_read_b64.
// Partials accumulated into global y via atomicAdd.
// ---------------------------------------------------------------------------
__global__ __launch_bounds__(256) void partial_kernel(const float* __restrict__ x,
                                                      const float* __restrict__ Wt,
                                                      const float* __restrict__ Wb,
                                                      const int* __restrict__ list,
                                                      const int* __restrict__ offs,
                                                      float* __restrict__ ytop,
                                                      float* __restrict__ ybot) {
    __shared__ __align__(16) float xs[256 * XP];
    const int tid = threadIdx.x;
    const int w = tid >> 6, l = tid & 63;
    const int bi = blockIdx.x;
    const bool isBot = (bi < NBOT_BLOCKS);

    int k, o, n, ycols;
    const float* W;
    float* y;
    if (isBot) {
        int c = bi >> 2; k = bi & 3;
        o = offs[c]; n = offs[c + 1] - o;
        W = Wb + (size_t)c * (NHID * NTPC);
        y = ybot; ycols = NTPC;
    } else {
        int b2 = bi - NBOT_BLOCKS;
        int st = b2 >> 2; k = b2 & 3;
        o = st * 16; n = 16;
        W = Wt; y = ytop; ycols = NCLS;
    }
    const int hbase = k * 256;

    for (int tile = 0; tile * 16 < n; ++tile) {
        if (tile) __syncthreads();
        // stage 16 sample rows (chunk of 256 floats each) into xs[h][i]
        for (int i = 0; i < 16; ++i) {
            int idx = tile * 16 + i;
            int s = isBot ? list[o + min(idx, n - 1)] : (o + i);
            xs[tid * XP + i] = x[(size_t)s * NHID + hbase + tid];
        }
        __syncthreads();
        const int nt = min(n - tile * 16, 16);
        if (4 * w < nt) {
            float acc[4][4];
#pragma unroll
            for (int m = 0; m < 4; ++m)
#pragma unroll
                for (int g = 0; g < 4; ++g) acc[m][g] = 0.f;
            const float* wr = W + (size_t)hbase * ycols + l;
#pragma unroll 4
            for (int h = 0; h < 256; ++h) {
                float2 xa = *(const float2*)&xs[h * XP + 4 * w];
                float2 xb = *(const float2*)&xs[h * XP + 4 * w + 2];
                float wv[4];
                wv[0] = wr[0];
                wv[1] = wr[64];
                wv[2] = wr[128];
                wv[3] = (192 + l < ycols) ? wr[192] : 0.f;
                const float xm[4] = {xa.x, xa.y, xb.x, xb.y};
#pragma unroll
                for (int m = 0; m < 4; ++m)
#pragma unroll
                    for (int g = 0; g < 4; ++g)
                        acc[m][g] = fmaf(xm[m], wv[g], acc[m][g]);
                wr += ycols;
            }
            const int smax = min(nt - 4 * w, 4);
            for (int m = 0; m < smax; ++m) {
                int idx = tile * 16 + 4 * w + m;
                int s = isBot ? list[o + idx] : (o + 4 * w + m);
                float* yr = y + (size_t)s * ycols;
#pragma unroll
                for (int g = 0; g < 4; ++g) {
                    int col = l + 64 * g;
                    if (col < ycols) atomicAdd(&yr[col], acc[m][g]);
                }
            }
        }
    }
}

// ---------------------------------------------------------------------------
// Pass 2: per-sample dual softmax + product. One wave per sample.
// ---------------------------------------------------------------------------
__global__ __launch_bounds__(256) void finalize_kernel(const float* __restrict__ ytop,
                                                       const float* __restrict__ ybot,
                                                       const float* __restrict__ bt,
                                                       const float* __restrict__ bb,
                                                       const int* __restrict__ cls,
                                                       const int* __restrict__ pos,
                                                       float* __restrict__ out) {
    const int w = threadIdx.x >> 6, l = threadIdx.x & 63;
    const int s = blockIdx.x * 4 + w;
    const int c = cls[s], p = pos[s];

    // --- top softmax, selected prob at column c ---
    float v[4];
#pragma unroll
    for (int g = 0; g < 4; ++g) {
        int col = l + 64 * g;
        v[g] = (col < NCLS) ? ytop[(size_t)s * NCLS + col] + bt[col] : -INFINITY;
    }
    float mx = fmaxf(fmaxf(v[0], v[1]), fmaxf(v[2], v[3]));
#pragma unroll
    for (int off = 32; off; off >>= 1) mx = fmaxf(mx, __shfl_xor(mx, off));
    float sum = 0.f, tc = 0.f;
#pragma unroll
    for (int g = 0; g < 4; ++g) {
        int col = l + 64 * g;
        float e = (col < NCLS) ? __expf(v[g] - mx) : 0.f;
        sum += e;
        if (col == c) tc = e;
    }
#pragma unroll
    for (int off = 32; off; off >>= 1) {
        sum += __shfl_xor(sum, off);
        tc  += __shfl_xor(tc, off);      // only one lane nonzero -> broadcast
    }
    const float tp = tc / sum;

    // --- bottom softmax, selected prob at column p ---
#pragma unroll
    for (int g = 0; g < 4; ++g) {
        int col = l + 64 * g;
        v[g] = (col < NTPC) ? ybot[(size_t)s * NTPC + col] + bb[c * NTPC + col] : -INFINITY;
    }
    mx = fmaxf(fmaxf(v[0], v[1]), fmaxf(v[2], v[3]));
#pragma unroll
    for (int off = 32; off; off >>= 1) mx = fmaxf(mx, __shfl_xor(mx, off));
    float bsum = 0.f;
    float ep = 0.f;
#pragma unroll
    for (int g = 0; g < 4; ++g) {
        int col = l + 64 * g;
        float e = (col < NTPC) ? __expf(v[g] - mx) : 0.f;
        bsum += e;
        if (col == p) ep = e;
    }
#pragma unroll
    for (int off = 32; off; off >>= 1) bsum += __shfl_xor(bsum, off);
    if (ep != 0.f || (l == (p & 63) && (l + 64 * (p >> 6) == p)))
        ;  // (keep simple: the owning lane writes below)
    int owner = ((l + 64 * 0 == p) || (l + 64 * 1 == p) || (l + 64 * 2 == p) || (l + 64 * 3 == p));
    if (owner) out[s] = tp * ep / bsum;
}

extern "C" void kernel_launch(void* const* d_in, const int* in_sizes, int n_in,
                              void* d_out, int out_size, void* d_ws, size_t ws_size,
                              hipStream_t stream) {
    const float* inputs = (const float*)d_in[0];
    const int*   labels = (const int*)d_in[1];
    const float* topW   = (const float*)d_in[2];
    const float* topB   = (const float*)d_in[3];
    const float* botW   = (const float*)d_in[4];
    const float* botB   = (const float*)d_in[5];
    float* out = (float*)d_out;

    char* ws   = (char*)d_ws;
    int*   cls = (int*)(ws + CLS_OFF);
    int*   pos = (int*)(ws + POS_OFF);
    int*   lst = (int*)(ws + LIST_OFF);
    int*   off = (int*)(ws + OFFS_OFF);
    float* ytop = (float*)(ws + YTOP_OFF);
    float* ybot = (float*)(ws + YBOT_OFF);

    hipMemsetAsync(ws + YTOP_OFF, 0, YTOP_BYTES + YBOT_BYTES, stream);
    group_kernel<<<1, 256, 0, stream>>>(labels, cls, pos, lst, off);
    partial_kernel<<<NBOT_BLOCKS + NTOP_BLOCKS, 256, 0, stream>>>(
        inputs, topW, botW, lst, off, ytop, ybot);
    finalize_kernel<<<BATCH / 4, 256, 0, stream>>>(ytop, ybot, topB, botB, cls, pos, out);
}

// Round 4
// 344.329 us; speedup vs baseline: 1.3883x; 1.0002x over previous
//
#include <hip/hip_runtime.h>
#include <math.h>

#define NHID  1024
#define NCLS  224
#define NTPC  225
#define BATCH 2048

#define NBOT_BLOCKS (NCLS * 4)      // class c, K-chunk k (256 rows each)
#define NTOP_BLOCKS (128 * 4)       // sample-tile st, K-chunk k

// ws layout (bytes):
#define CLS_OFF  0
#define POS_OFF  8192
#define LIST_OFF 16384
#define OFFS_OFF 24576
#define YTOP_OFF 32768
#define YTOP_BYTES (BATCH * NCLS * 4)
#define YBOT_OFF (YTOP_OFF + YTOP_BYTES)
#define YBOT_BYTES (BATCH * NTPC * 4)

// ---------------------------------------------------------------------------
// Pass 0: label decode (int32/int64 autodetect), class/pos, group-by-class.
// ---------------------------------------------------------------------------
__global__ __launch_bounds__(256) void group_kernel(const int* __restrict__ labels,
                                                    int* __restrict__ cls,
                                                    int* __restrict__ pos,
                                                    int* __restrict__ list,
                                                    int* __restrict__ offs) {
    __shared__ int cnt[NCLS];
    __shared__ int sc[256];
    __shared__ int bex[NCLS];
    __shared__ int nz;
    const int tid = threadIdx.x;
    if (tid == 0) nz = 0;
    for (int j = tid; j < NCLS; j += 256) cnt[j] = 0;
    __syncthreads();
    int loc = 0;
    for (int k = 0; k < 4; ++k) {
        int i = tid + 256 * k;
        if (labels[2 * i + 1] != 0) loc = 1;
    }
    if (loc) atomicOr(&nz, 1);
    __syncthreads();
    const bool is64 = (nz == 0);
    int myc[8], myr[8];
#pragma unroll
    for (int k = 0; k < 8; ++k) {
        int i = tid + 256 * k;
        int l = is64 ? labels[2 * i] : labels[i];
        int c = l / NTPC;
        cls[i] = c;
        pos[i] = l - c * NTPC;
        myc[k] = c;
        myr[k] = atomicAdd(&cnt[c], 1);
    }
    __syncthreads();
    int v = (tid < NCLS) ? cnt[tid] : 0;
    sc[tid] = v;
    __syncthreads();
    for (int off = 1; off < 256; off <<= 1) {
        int u = (tid >= off) ? sc[tid - off] : 0;
        __syncthreads();
        sc[tid] += u;
        __syncthreads();
    }
    if (tid < NCLS) {
        int ex = sc[tid] - v;
        bex[tid] = ex;
        offs[tid] = ex;
    }
    if (tid == 0) offs[NCLS] = BATCH;
    __syncthreads();
#pragma unroll
    for (int k = 0; k < 8; ++k) {
        int i = tid + 256 * k;
        list[bex[myc[k]] + myr[k]] = i;
    }
}

// ---------------------------------------------------------------------------
// Pass 1 (fused): K-split partial GEMMs. 256 threads = 4 waves.
// Wave w owns COLUMN group 64w..64w+63 (lane l -> col 64w+l); acc[16] over
// the 16 tile samples => each wave loads only its quarter of the W chunk:
// ONE global_load_dword per h-row, 16 FMAs per load, unroll 8 in flight.
// x tile in LDS xs[h][16], XOR-group swizzle: sample-quad a of row h stored
// at quad (a ^ ((h>>1)&3)) -> staging writes 8-way conflict (cheap), compute
// reads are lane-uniform ds_read_b128 broadcasts (conflict-free).
// Partials accumulated into global y via atomicAdd (4 K-chunks collide).
// ---------------------------------------------------------------------------
__global__ __launch_bounds__(256) void partial_kernel(const float* __restrict__ x,
                                                      const float* __restrict__ Wt,
                                                      const float* __restrict__ Wb,
                                                      const int* __restrict__ list,
                                                      const int* __restrict__ offs,
                                                      float* __restrict__ ytop,
                                                      float* __restrict__ ybot) {
    __shared__ __align__(16) float xs[256 * 16];   // 16 KB
    const int tid = threadIdx.x;
    const int w = tid >> 6, l = tid & 63;
    const int bi = blockIdx.x;
    const bool isBot = (bi < NBOT_BLOCKS);

    int k, o, n, ycols;
    const float* W;
    float* y;
    if (isBot) {
        int c = bi >> 2; k = bi & 3;
        o = offs[c]; n = offs[c + 1] - o;
        W = Wb + (size_t)c * (NHID * NTPC);
        y = ybot; ycols = NTPC;
    } else {
        int b2 = bi - NBOT_BLOCKS;
        int st = b2 >> 2; k = b2 & 3;
        o = st * 16; n = 16;
        W = Wt; y = ytop; ycols = NCLS;
    }
    const int hbase = k * 256;
    const int col   = 64 * w + l;
    const int colc  = min(col, ycols - 1);          // clamp for safe loads
    const bool colok = (col < ycols);
    const int hq = (tid >> 1) & 3;                  // staging swizzle key (h=tid)

    for (int tile = 0; tile * 16 < n; ++tile) {
        if (tile) __syncthreads();                  // xs reuse vs prior compute reads
        // stage: thread tid == row h of this chunk; 16 coalesced loads
        const float* xcol = x + hbase + tid;
#pragma unroll
        for (int i = 0; i < 16; ++i) {
            int idx = tile * 16 + i;
            int s = isBot ? list[o + min(idx, n - 1)] : (o + i);
            xs[(tid << 4) + ((((i >> 2) ^ hq) << 2) | (i & 3))] = xcol[(size_t)s * NHID];
        }
        __syncthreads();

        float acc[16];
#pragma unroll
        for (int i = 0; i < 16; ++i) acc[i] = 0.f;

        const float* wr = W + (size_t)hbase * ycols + colc;
#pragma unroll 8
        for (int h = 0; h < 256; ++h) {
            float wv = wr[0];
            const float4* xr = (const float4*)&xs[h << 4];
            const int q = (h >> 1) & 3;
            float4 x0 = xr[q];          // sample quad 0 lives at slot 0^q
            float4 x1 = xr[1 ^ q];
            float4 x2 = xr[2 ^ q];
            float4 x3 = xr[3 ^ q];
            acc[0]  = fmaf(x0.x, wv, acc[0]);
            acc[1]  = fmaf(x0.y, wv, acc[1]);
            acc[2]  = fmaf(x0.z, wv, acc[2]);
            acc[3]  = fmaf(x0.w, wv, acc[3]);
            acc[4]  = fmaf(x1.x, wv, acc[4]);
            acc[5]  = fmaf(x1.y, wv, acc[5]);
            acc[6]  = fmaf(x1.z, wv, acc[6]);
            acc[7]  = fmaf(x1.w, wv, acc[7]);
            acc[8]  = fmaf(x2.x, wv, acc[8]);
            acc[9]  = fmaf(x2.y, wv, acc[9]);
            acc[10] = fmaf(x2.z, wv, acc[10]);
            acc[11] = fmaf(x2.w, wv, acc[11]);
            acc[12] = fmaf(x3.x, wv, acc[12]);
            acc[13] = fmaf(x3.y, wv, acc[13]);
            acc[14] = fmaf(x3.z, wv, acc[14]);
            acc[15] = fmaf(x3.w, wv, acc[15]);
            wr += ycols;
        }

        const int nt = min(n - tile * 16, 16);
        if (colok) {
            for (int i = 0; i < nt; ++i) {
                int s = isBot ? list[o + tile * 16 + i] : (o + i);
                atomicAdd(&y[(size_t)s * ycols + col], acc[i]);
            }
        }
    }
}

// ---------------------------------------------------------------------------
// Pass 2: per-sample dual softmax + product. One wave per sample.
// ---------------------------------------------------------------------------
__global__ __launch_bounds__(256) void finalize_kernel(const float* __restrict__ ytop,
                                                       const float* __restrict__ ybot,
                                                       const float* __restrict__ bt,
                                                       const float* __restrict__ bb,
                                                       const int* __restrict__ cls,
                                                       const int* __restrict__ pos,
                                                       float* __restrict__ out) {
    const int w = threadIdx.x >> 6, l = threadIdx.x & 63;
    const int s = blockIdx.x * 4 + w;
    const int c = cls[s], p = pos[s];

    float v[4];
#pragma unroll
    for (int g = 0; g < 4; ++g) {
        int col = l + 64 * g;
        v[g] = (col < NCLS) ? ytop[(size_t)s * NCLS + col] + bt[col] : -INFINITY;
    }
    float mx = fmaxf(fmaxf(v[0], v[1]), fmaxf(v[2], v[3]));
#pragma unroll
    for (int off = 32; off; off >>= 1) mx = fmaxf(mx, __shfl_xor(mx, off));
    float sum = 0.f, tc = 0.f;
#pragma unroll
    for (int g = 0; g < 4; ++g) {
        int col = l + 64 * g;
        float e = (col < NCLS) ? __expf(v[g] - mx) : 0.f;
        sum += e;
        if (col == c) tc = e;
    }
#pragma unroll
    for (int off = 32; off; off >>= 1) {
        sum += __shfl_xor(sum, off);
        tc  += __shfl_xor(tc, off);
    }
    const float tp = tc / sum;

#pragma unroll
    for (int g = 0; g < 4; ++g) {
        int col = l + 64 * g;
        v[g] = (col < NTPC) ? ybot[(size_t)s * NTPC + col] + bb[c * NTPC + col] : -INFINITY;
    }
    mx = fmaxf(fmaxf(v[0], v[1]), fmaxf(v[2], v[3]));
#pragma unroll
    for (int off = 32; off; off >>= 1) mx = fmaxf(mx, __shfl_xor(mx, off));
    float bsum = 0.f, ep = 0.f;
#pragma unroll
    for (int g = 0; g < 4; ++g) {
        int col = l + 64 * g;
        float e = (col < NTPC) ? __expf(v[g] - mx) : 0.f;
        bsum += e;
        if (col == p) ep = e;
    }
#pragma unroll
    for (int off = 32; off; off >>= 1) bsum += __shfl_xor(bsum, off);
    int owner = ((l == (p & 63)) && ((p >> 6) == ((l + 64 * ((p >> 6))) == p ? (p >> 6) : -1)));
    // simpler: the lane whose one of its 4 cols equals p writes
#pragma unroll
    for (int g = 0; g < 4; ++g)
        if (l + 64 * g == p) out[s] = tp * ep / bsum;
    (void)owner;
}

extern "C" void kernel_launch(void* const* d_in, const int* in_sizes, int n_in,
                              void* d_out, int out_size, void* d_ws, size_t ws_size,
                              hipStream_t stream) {
    const float* inputs = (const float*)d_in[0];
    const int*   labels = (const int*)d_in[1];
    const float* topW   = (const float*)d_in[2];
    const float* topB   = (const float*)d_in[3];
    const float* botW   = (const float*)d_in[4];
    const float* botB   = (const float*)d_in[5];
    float* out = (float*)d_out;

    char* ws   = (char*)d_ws;
    int*   cls = (int*)(ws + CLS_OFF);
    int*   pos = (int*)(ws + POS_OFF);
    int*   lst = (int*)(ws + LIST_OFF);
    int*   off = (int*)(ws + OFFS_OFF);
    float* ytop = (float*)(ws + YTOP_OFF);
    float* ybot = (float*)(ws + YBOT_OFF);

    hipMemsetAsync(ws + YTOP_OFF, 0, YTOP_BYTES + YBOT_BYTES, stream);
    group_kernel<<<1, 256, 0, stream>>>(labels, cls, pos, lst, off);
    partial_kernel<<<NBOT_BLOCKS + NTOP_BLOCKS, 256, 0, stream>>>(
        inputs, topW, botW, lst, off, ytop, ybot);
    finalize_kernel<<<BATCH / 4, 256, 0, stream>>>(ytop, ybot, topB, botB, cls, pos, out);
}